// Round 20
// baseline (88.901 us; speedup 1.0000x reference)
//
#include <hip/hip_runtime.h>
#include <hip/hip_bf16.h>
#include <math.h>

#define NN    87
#define NN2   (NN * NN)          // 7569
#define EPW   92                 // panel width
#define EF1   (NN * EPW + 8)     // 8012 floats per E buffer (incl zero tail)
#define SDN   (NN * EPW + 4)     // 8008 shorts: sD/sA + zero tail
#define WPH   104                // ws W-panel row stride (shorts)
#define WPANEL (96 * WPH)        // 9984 shorts
#define NT    256
#define GRIDB 512                // 2 blocks/CU, 8 batches per block

// ws layout (bytes)
#define PAD_N    8360
#define WS_W     0               // 2 bf16 W panels: 39936 B
#define WS_EPAD  (2 * WPANEL * 2)
#define WS_XPAD  (WS_EPAD + PAD_N * 4)
#define WS_NEED  (WS_XPAD + PAD_N * 4)

typedef __attribute__((ext_vector_type(8))) short bf16x8;
typedef __attribute__((ext_vector_type(4))) short bf16x4;
typedef __attribute__((ext_vector_type(4))) float f32x4;
typedef float f32x4u __attribute__((ext_vector_type(4), aligned(4)));

__device__ __forceinline__ short f2bf(float f) {
    __hip_bfloat16 h = __float2bfloat16(f);
    return *(short*)&h;
}

__device__ __forceinline__ void gl16(const float* g, float* l) {
    __builtin_amdgcn_global_load_lds(
        (const __attribute__((address_space(1))) void*)g,
        (__attribute__((address_space(3))) void*)l, 16, 0, 0);
}

// W panels + padded copies of LAST batch's E and x
__global__ void prep(const float* __restrict__ W, const float* __restrict__ evecs,
                     const float* __restrict__ x, int B, char* __restrict__ ws)
{
    int idx = (int)blockIdx.x * NT + (int)threadIdx.x;
    short* wpp = (short*)(ws + WS_W);
    float* ep  = (float*)(ws + WS_EPAD);
    float* xp  = (float*)(ws + WS_XPAD);
    if (idx < 2 * WPANEL) {
        int p = idx / WPANEL, rem = idx - p * WPANEL;
        int r = rem / WPH, c = rem - r * WPH;
        short v = 0;
        if (r < NN && c < NN) v = f2bf(W[r * (2 * NN) + p * NN + c]);
        wpp[idx] = v;
    }
    int i2 = idx - 2 * WPANEL;
    if (i2 >= 0 && i2 < PAD_N) ep[i2] = (i2 < NN2) ? evecs[(size_t)(B - 1) * NN2 + i2] : 0.f;
    int i3 = i2 - PAD_N;
    if (i3 >= 0 && i3 < PAD_N) xp[i3] = (i3 < NN2) ? x[(size_t)(B - 1) * NN2 + i3] : 0.f;
}

template <bool WS>
__device__ __forceinline__ bf16x8 wload(const short* __restrict__ wp,
                                        const float* __restrict__ gW,
                                        int panel, int jrow, int jcl, int k0, bool tailKs)
{
    if constexpr (WS) {
        return *(const bf16x8*)&wp[panel * WPANEL + jrow * WPH + k0];
    } else {
        float v[8];
        if (!tailKs) {
            f32x4u a  = *(const f32x4u*)(gW + jcl * (2 * NN) + panel * NN + k0);
            f32x4u b4 = *(const f32x4u*)(gW + jcl * (2 * NN) + panel * NN + k0 + 4);
            v[0] = a.x; v[1] = a.y; v[2] = a.z; v[3] = a.w;
            v[4] = b4.x; v[5] = b4.y; v[6] = b4.z; v[7] = b4.w;
        } else {
            #pragma unroll
            for (int q = 0; q < 8; ++q) {
                int k = k0 + q;
                v[q] = (k < NN) ? gW[jcl * (2 * NN) + panel * NN + k] : 0.f;
            }
        }
        bf16x8 o;
        #pragma unroll
        for (int q = 0; q < 8; ++q) o[q] = f2bf(v[q]);
        return o;
    }
}

// Stage one batch's E into a given sE buffer
template <bool WS>
__device__ __forceinline__ void stageE(const float* __restrict__ Eb, float* __restrict__ sEb,
                                       int tid, int wave, int lane)
{
    if constexpr (WS) {
        for (int vc = wave; vc < 32; vc += 4) {
            int p   = vc * 256 + lane * 4;
            int row = p / EPW;
            int col = p - row * EPW;
            const float* g = Eb + row * NN + col;   // col>=87 spills to next row: finite, masked
            if (vc < 31) gl16(g, &sEb[vc * 256]);
            else if (lane < 17) gl16(g, &sEb[vc * 256]);
        }
    } else {
        for (int u = tid; u < NN * 22; u += NT) {
            int r = u / 22, sg = u - r * 22, c = sg * 4;
            const float* pE = Eb + r * NN + c;
            if (sg < 21) *(f32x4*)&sEb[r * EPW + c] = *(const f32x4u*)pE;
            else { f32x4 t; t.x = pE[0]; t.y = pE[1]; t.z = pE[2]; t.w = 0.f;
                   *(f32x4*)&sEb[r * EPW + c] = t; }
        }
        for (int u = tid; u < NN * 4; u += NT) {
            int r = u >> 2, c = 88 + (u & 3);
            sEb[r * EPW + c] = 0.f;
        }
    }
}

template <bool WS>
__global__ __launch_bounds__(NT, 2)
void fused(const float* __restrict__ gx, const float* __restrict__ gevals,
           const float* __restrict__ gevecs, const float* __restrict__ dtime,
           const float* __restrict__ gW, const float* __restrict__ bias,
           const char* __restrict__ ws, int B, int gridB, float* __restrict__ out)
{
    __shared__ __align__(16) float sE[2][EF1];   // 64096 B (double-buffered E)
    __shared__ __align__(16) short sD[SDN];      // 16016 B; phase-aliased as sA
    __shared__ float sLam[2][96];                // 768 B
    __shared__ float sT[88];                     // clamped diffusion times
    // total ~81.2 KB -> 2 blocks/CU

    short* const sA = sD;                        // A-panel aliases the D region

    const int tid  = (int)threadIdx.x;
    const int lane = tid & 63;
    const int wave = tid >> 6;
    const int l15  = lane & 15;
    const int lk   = lane >> 4;
    const int i0   = (wave >> 1) * 48;
    const int j0   = (wave & 1) * 48;

    const short* wp   = nullptr;
    const float* epad = nullptr;
    const float* xpad = nullptr;
    if constexpr (WS) {
        wp   = (const short*)(ws + WS_W);
        epad = (const float*)(ws + WS_EPAD);
        xpad = (const float*)(ws + WS_XPAD);
    }

    int iw[3], jw[3], iru[3], jru[3];
    #pragma unroll
    for (int r = 0; r < 3; ++r) {
        iw[r]  = i0 + 16 * r + l15;
        jw[r]  = j0 + 16 * r + l15;
        iru[r] = (iw[r] < NN) ? iw[r] : NN - 1;
        jru[r] = (jw[r] < NN) ? jw[r] : NN - 1;
    }

    // ---- batch-invariant: W fragments (held in regs for ALL iterations) + bias ----
    bf16x8 wfx[3][3], wfd[3][3];
    #pragma unroll
    for (int ks = 0; ks < 3; ++ks)
        #pragma unroll
        for (int wr = 0; wr < 3; ++wr) {
            wfx[ks][wr] = wload<WS>(wp, gW, 0, jw[wr], jru[wr], ks * 32 + lk * 8, ks == 2);
            wfd[ks][wr] = wload<WS>(wp, gW, 1, jw[wr], jru[wr], ks * 32 + lk * 8, ks == 2);
        }
    float bjv[3][4];
    #pragma unroll
    for (int wr = 0; wr < 3; ++wr) {
        const int jb = j0 + 16 * wr + lk * 4;
        if (jb + 3 < NN) {
            f32x4u t = *(const f32x4u*)(bias + jb);
            bjv[wr][0] = t.x; bjv[wr][1] = t.y; bjv[wr][2] = t.z; bjv[wr][3] = t.w;
        } else {
            #pragma unroll
            for (int q = 0; q < 4; ++q) bjv[wr][q] = (jb + q < NN) ? bias[jb + q] : 0.f;
        }
    }

    // zero tails + sT once
    if (tid < 8) { sE[0][NN * EPW + tid] = 0.f; sE[1][NN * EPW + tid] = 0.f; }
    if (tid < 4) sD[NN * EPW + tid] = 0;         // tail never overwritten (sA<8004, D guarded)
    if (tid < NN) sT[tid] = fmaxf(dtime[tid], 1e-8f);

    // ---- prologue: stage batch b0 into buffer 0 ----
    const int b0 = (int)blockIdx.x;
    {
        const float* Eb = gevecs + (size_t)b0 * NN2;
        if (WS && b0 == B - 1) Eb = epad;
        stageE<WS>(Eb, sE[0], tid, wave, lane);
        if (tid < 96) sLam[0][tid] = (tid < NN) ? gevals[(size_t)b0 * NN + tid] : 3e38f;
    }
    __syncthreads();   // E(b0) + sLam[0] + sT ready

    // ---- persistent loop ----
    for (int it = 0, b = b0; b < B; ++it, b += gridB) {
        const int  p  = it & 1;
        const int  bn = b + gridB;
        const bool hn = bn < B;

        // ===== TOP: prefetch next E (buffer last read a full iteration ago) =====
        if (hn) {
            const float* Ebn = gevecs + (size_t)bn * NN2;
            if (WS && bn == B - 1) Ebn = epad;
            stageE<WS>(Ebn, sE[1 - p], tid, wave, lane);
        }
        float lamn = 3e38f;
        if (hn && tid < NN) lamn = gevals[(size_t)bn * NN + tid];

        const float* sEp = sE[p];

        // ===== A-panel: sA[i][k] = bf16(E[i,k] * exp(-t_i lam_k)), computed ONCE =====
        // cols 87..91 become exact zeros via lam=3e38. 2001 quads over 256 threads.
        #pragma unroll
        for (int m = 0; m < 8; ++m) {
            const int q4 = tid + m * NT;
            if (q4 < 2001) {
                const int off = q4 * 4;
                const int i = off / EPW;
                const int k = off - i * EPW;
                f32x4 ev = *(const f32x4*)&sEp[off];
                const float t = sT[i];
                bf16x4 v;
                v[0] = f2bf(ev.x * __expf(-t * sLam[p][k]));
                v[1] = f2bf(ev.y * __expf(-t * sLam[p][k + 1]));
                v[2] = f2bf(ev.z * __expf(-t * sLam[p][k + 2]));
                v[3] = f2bf(ev.w * __expf(-t * sLam[p][k + 3]));
                *(bf16x4*)&sA[off] = v;
            }
        }

        // ===== bar_A (raw: lgkm drain only — DMA stays in flight): sA visible =====
        asm volatile("s_waitcnt lgkmcnt(0)" ::: "memory");
        __builtin_amdgcn_s_barrier();
        __builtin_amdgcn_sched_barrier(0);

        // ===== GEMM1: D = A @ E^T  (af = pure ds_reads from sA) =====
        f32x4 acc1[3][3];
        #pragma unroll
        for (int c = 0; c < 3; ++c)
            #pragma unroll
            for (int r = 0; r < 3; ++r) acc1[c][r] = (f32x4){0.f, 0.f, 0.f, 0.f};

        #pragma unroll
        for (int ks = 0; ks < 3; ++ks) {
            const int k0 = ks * 32 + lk * 8;
            bf16x8 ef[3], af[3];
            #pragma unroll
            for (int c = 0; c < 3; ++c) {
                f32x4 lo = *(const f32x4*)&sEp[jru[c] * EPW + k0];
                f32x4 hi = *(const f32x4*)&sEp[jru[c] * EPW + k0 + 4];
                #pragma unroll
                for (int q = 0; q < 4; ++q) { ef[c][q] = f2bf(lo[q]); ef[c][q + 4] = f2bf(hi[q]); }
            }
            const bool hiZero = (ks == 2) && (lk == 3);   // k 92..95: sA has no pad there
            #pragma unroll
            for (int r = 0; r < 3; ++r) {
                bf16x4 lo = *(const bf16x4*)&sA[iru[r] * EPW + k0];
                bf16x4 hi;
                if (hiZero) hi = (bf16x4){0, 0, 0, 0};
                else        hi = *(const bf16x4*)&sA[iru[r] * EPW + k0 + 4];
                #pragma unroll
                for (int q = 0; q < 4; ++q) { af[r][q] = lo[q]; af[r][q + 4] = hi[q]; }
            }
            #pragma unroll
            for (int c = 0; c < 3; ++c)
                #pragma unroll
                for (int r = 0; r < 3; ++r)
                    acc1[c][r] = __builtin_amdgcn_mfma_f32_16x16x32_bf16(ef[c], af[r], acc1[c][r], 0, 0, 0);
        }

        // ===== x fragments for CURRENT batch (issued now; consumed after bar_C) =====
        const float* xbb = gx + (size_t)b * NN2;
        bool xvec = true;
        if (b == B - 1) { if (WS) xbb = xpad; else xvec = false; }
        float xr[3][3][8];
        #pragma unroll
        for (int xc = 0; xc < 3; ++xc)
            #pragma unroll
            for (int ks = 0; ks < 3; ++ks) {
                const int off = iru[xc] * NN + ks * 32 + lk * 8;
                if (xvec) {
                    f32x4u a  = *(const f32x4u*)(xbb + off);
                    f32x4u b4 = *(const f32x4u*)(xbb + off + 4);
                    xr[xc][ks][0] = a.x;  xr[xc][ks][1] = a.y;
                    xr[xc][ks][2] = a.z;  xr[xc][ks][3] = a.w;
                    xr[xc][ks][4] = b4.x; xr[xc][ks][5] = b4.y;
                    xr[xc][ks][6] = b4.z; xr[xc][ks][7] = b4.w;
                } else {
                    #pragma unroll
                    for (int q = 0; q < 8; ++q) {
                        int o = off + q;
                        xr[xc][ks][q] = xbb[(o < NN2) ? o : (NN2 - 1)];
                    }
                }
            }

        // ===== bar_B (raw): all waves' sA reads done -> region may be overwritten by D =====
        asm volatile("s_waitcnt lgkmcnt(0)" ::: "memory");
        __builtin_amdgcn_s_barrier();
        __builtin_amdgcn_sched_barrier(0);

        // ===== D -> sD (overwrites sA; acc1 dies here) =====
        #pragma unroll
        for (int c = 0; c < 3; ++c) {
            const int jb = j0 + 16 * c + lk * 4;
            if (jb < EPW) {
                #pragma unroll
                for (int r = 0; r < 3; ++r) {
                    if (iw[r] < NN) {
                        bf16x4 v = {f2bf(acc1[c][r][0]), f2bf(acc1[c][r][1]),
                                    f2bf(acc1[c][r][2]), f2bf(acc1[c][r][3])};
                        *(bf16x4*)&sD[iw[r] * EPW + jb] = v;
                    }
                }
            }
        }
        // sLam for next batch (disjoint buffer; read only after next __syncthreads)
        if (hn && tid < 96) sLam[1 - p][tid] = (tid < NN) ? lamn : 3e38f;

        // ===== bar_C (raw): sD visible; DMA + x loads stay in flight =====
        asm volatile("s_waitcnt lgkmcnt(0)" ::: "memory");
        __builtin_amdgcn_s_barrier();
        __builtin_amdgcn_sched_barrier(0);

        // ===== GEMM2: out = x@W1^T + D@W2^T (W from regs; bias pre-folded) =====
        f32x4 acc2[3][3];
        #pragma unroll
        for (int wr = 0; wr < 3; ++wr)
            #pragma unroll
            for (int xc = 0; xc < 3; ++xc) {
                acc2[wr][xc][0] = bjv[wr][0]; acc2[wr][xc][1] = bjv[wr][1];
                acc2[wr][xc][2] = bjv[wr][2]; acc2[wr][xc][3] = bjv[wr][3];
            }

        #pragma unroll
        for (int ks = 0; ks < 3; ++ks) {
            bf16x8 xf[3];
            #pragma unroll
            for (int xc = 0; xc < 3; ++xc)
                #pragma unroll
                for (int q = 0; q < 8; ++q) xf[xc][q] = f2bf(xr[xc][ks][q]);
            #pragma unroll
            for (int wr = 0; wr < 3; ++wr)
                #pragma unroll
                for (int xc = 0; xc < 3; ++xc)
                    acc2[wr][xc] = __builtin_amdgcn_mfma_f32_16x16x32_bf16(
                        wfx[ks][wr], xf[xc], acc2[wr][xc], 0, 0, 0);
        }
        #pragma unroll
        for (int ks = 0; ks < 3; ++ks) {
            const int k0 = ks * 32 + lk * 8;
            bf16x8 df[3];
            #pragma unroll
            for (int xc = 0; xc < 3; ++xc) {
                bf16x4 lo = *(const bf16x4*)&sD[iru[xc] * EPW + k0];
                bf16x4 hi = *(const bf16x4*)&sD[iru[xc] * EPW + k0 + 4];
                #pragma unroll
                for (int q = 0; q < 4; ++q) { df[xc][q] = lo[q]; df[xc][q + 4] = hi[q]; }
            }
            #pragma unroll
            for (int wr = 0; wr < 3; ++wr)
                #pragma unroll
                for (int xc = 0; xc < 3; ++xc)
                    acc2[wr][xc] = __builtin_amdgcn_mfma_f32_16x16x32_bf16(
                        wfd[ks][wr], df[xc], acc2[wr][xc], 0, 0, 0);
        }

        // ===== direct vectorized stores =====
        {
            float* __restrict__ gb = out + (size_t)b * NN2;
            #pragma unroll
            for (int wr = 0; wr < 3; ++wr) {
                const int jb = j0 + 16 * wr + lk * 4;
                #pragma unroll
                for (int xc = 0; xc < 3; ++xc) {
                    const int i = iw[xc];
                    if (i < NN) {
                        if (jb + 3 < NN) {
                            f32x4u v;
                            v.x = acc2[wr][xc][0]; v.y = acc2[wr][xc][1];
                            v.z = acc2[wr][xc][2]; v.w = acc2[wr][xc][3];
                            *(f32x4u*)&gb[i * NN + jb] = v;
                        } else {
                            #pragma unroll
                            for (int q = 0; q < 4; ++q)
                                if (jb + q < NN) gb[i * NN + jb + q] = acc2[wr][xc][q];
                        }
                    }
                }
            }
        }

        // end-of-iter: vmcnt(0)+lgkmcnt(0)+barrier -> E(bn) + sLam ready
        if (hn) __syncthreads();
    }
}

extern "C" void kernel_launch(void* const* d_in, const int* in_sizes, int n_in,
                              void* d_out, int out_size, void* d_ws, size_t ws_size,
                              hipStream_t stream)
{
    const float* x     = (const float*)d_in[0];
    const float* evals = (const float*)d_in[1];
    const float* evecs = (const float*)d_in[2];
    const float* dtime = (const float*)d_in[3];
    const float* W     = (const float*)d_in[4];
    const float* bias  = (const float*)d_in[5];
    float* out = (float*)d_out;

    const int B = in_sizes[1] / NN;   // evals is (B, 87)
    const int gridB = (B < GRIDB) ? B : GRIDB;

    if (ws_size >= (size_t)WS_NEED) {
        const int prep_elems = 2 * WPANEL + 2 * PAD_N;
        prep<<<(prep_elems + NT - 1) / NT, NT, 0, stream>>>(W, evecs, x, B, (char*)d_ws);
        fused<true><<<dim3(gridB), dim3(NT), 0, stream>>>(x, evals, evecs, dtime, W, bias,
                                                          (const char*)d_ws, B, gridB, out);
    } else {
        fused<false><<<dim3(gridB), dim3(NT), 0, stream>>>(x, evals, evecs, dtime, W, bias,
                                                           nullptr, B, gridB, out);
    }
}

// Round 21
// 88.827 us; speedup vs baseline: 1.0008x; 1.0008x over previous
//
#include <hip/hip_runtime.h>
#include <hip/hip_bf16.h>
#include <math.h>

#define NN    87
#define NN2   (NN * NN)          // 7569
#define EPW   92                 // panel width
#define EF1   (NN * EPW + 8)     // 8012 floats per E buffer (incl zero tail)
#define SDN   (NN * EPW + 4)     // 8008 shorts: sD + zero tail
#define WPH   104                // ws W-panel row stride (shorts)
#define WPANEL (96 * WPH)        // 9984 shorts
#define NT    256
#define GRIDB 512                // 2 blocks/CU, 8 batches per block

// ws layout (bytes)
#define PAD_N    8360
#define WS_W     0               // 2 bf16 W panels: 39936 B
#define WS_EPAD  (2 * WPANEL * 2)
#define WS_XPAD  (WS_EPAD + PAD_N * 4)
#define WS_NEED  (WS_XPAD + PAD_N * 4)

typedef __attribute__((ext_vector_type(8))) short bf16x8;
typedef __attribute__((ext_vector_type(4))) short bf16x4;
typedef __attribute__((ext_vector_type(4))) float f32x4;
typedef float f32x4u __attribute__((ext_vector_type(4), aligned(4)));

__device__ __forceinline__ short f2bf(float f) {
    __hip_bfloat16 h = __float2bfloat16(f);
    return *(short*)&h;
}

__device__ __forceinline__ void gl16(const float* g, float* l) {
    __builtin_amdgcn_global_load_lds(
        (const __attribute__((address_space(1))) void*)g,
        (__attribute__((address_space(3))) void*)l, 16, 0, 0);
}

// W panels + padded copies of LAST batch's E and x
__global__ void prep(const float* __restrict__ W, const float* __restrict__ evecs,
                     const float* __restrict__ x, int B, char* __restrict__ ws)
{
    int idx = (int)blockIdx.x * NT + (int)threadIdx.x;
    short* wpp = (short*)(ws + WS_W);
    float* ep  = (float*)(ws + WS_EPAD);
    float* xp  = (float*)(ws + WS_XPAD);
    if (idx < 2 * WPANEL) {
        int p = idx / WPANEL, rem = idx - p * WPANEL;
        int r = rem / WPH, c = rem - r * WPH;
        short v = 0;
        if (r < NN && c < NN) v = f2bf(W[r * (2 * NN) + p * NN + c]);
        wpp[idx] = v;
    }
    int i2 = idx - 2 * WPANEL;
    if (i2 >= 0 && i2 < PAD_N) ep[i2] = (i2 < NN2) ? evecs[(size_t)(B - 1) * NN2 + i2] : 0.f;
    int i3 = i2 - PAD_N;
    if (i3 >= 0 && i3 < PAD_N) xp[i3] = (i3 < NN2) ? x[(size_t)(B - 1) * NN2 + i3] : 0.f;
}

template <bool WS>
__device__ __forceinline__ bf16x8 wload(const short* __restrict__ wp,
                                        const float* __restrict__ gW,
                                        int panel, int jrow, int jcl, int k0, bool tailKs)
{
    if constexpr (WS) {
        return *(const bf16x8*)&wp[panel * WPANEL + jrow * WPH + k0];
    } else {
        float v[8];
        if (!tailKs) {
            f32x4u a  = *(const f32x4u*)(gW + jcl * (2 * NN) + panel * NN + k0);
            f32x4u b4 = *(const f32x4u*)(gW + jcl * (2 * NN) + panel * NN + k0 + 4);
            v[0] = a.x; v[1] = a.y; v[2] = a.z; v[3] = a.w;
            v[4] = b4.x; v[5] = b4.y; v[6] = b4.z; v[7] = b4.w;
        } else {
            #pragma unroll
            for (int q = 0; q < 8; ++q) {
                int k = k0 + q;
                v[q] = (k < NN) ? gW[jcl * (2 * NN) + panel * NN + k] : 0.f;
            }
        }
        bf16x8 o;
        #pragma unroll
        for (int q = 0; q < 8; ++q) o[q] = f2bf(v[q]);
        return o;
    }
}

// Stage one batch's E into a given sE buffer
template <bool WS>
__device__ __forceinline__ void stageE(const float* __restrict__ Eb, float* __restrict__ sEb,
                                       int tid, int wave, int lane)
{
    if constexpr (WS) {
        for (int vc = wave; vc < 32; vc += 4) {
            int p   = vc * 256 + lane * 4;
            int row = p / EPW;
            int col = p - row * EPW;
            const float* g = Eb + row * NN + col;   // col>=87 spills to next row: finite, masked
            if (vc < 31) gl16(g, &sEb[vc * 256]);
            else if (lane < 17) gl16(g, &sEb[vc * 256]);
        }
    } else {
        for (int u = tid; u < NN * 22; u += NT) {
            int r = u / 22, sg = u - r * 22, c = sg * 4;
            const float* pE = Eb + r * NN + c;
            if (sg < 21) *(f32x4*)&sEb[r * EPW + c] = *(const f32x4u*)pE;
            else { f32x4 t; t.x = pE[0]; t.y = pE[1]; t.z = pE[2]; t.w = 0.f;
                   *(f32x4*)&sEb[r * EPW + c] = t; }
        }
        for (int u = tid; u < NN * 4; u += NT) {
            int r = u >> 2, c = 88 + (u & 3);
            sEb[r * EPW + c] = 0.f;
        }
    }
}

template <bool WS>
__global__ __launch_bounds__(NT, 2)
void fused(const float* __restrict__ gx, const float* __restrict__ gevals,
           const float* __restrict__ gevecs, const float* __restrict__ dtime,
           const float* __restrict__ gW, const float* __restrict__ bias,
           const char* __restrict__ ws, int B, int gridB, float* __restrict__ out)
{
    __shared__ __align__(16) float sE[2][EF1];   // 64096 B (double-buffered E)
    __shared__ __align__(16) short sD[SDN];      // 16016 B
    __shared__ float sLam[2][96];                // 768 B
    // total 80880 B -> 2 blocks/CU

    const int tid  = (int)threadIdx.x;
    const int lane = tid & 63;
    const int wave = tid >> 6;
    const int l15  = lane & 15;
    const int lk   = lane >> 4;
    const int i0   = (wave >> 1) * 48;
    const int j0   = (wave & 1) * 48;

    const short* wp   = nullptr;
    const float* epad = nullptr;
    const float* xpad = nullptr;
    if constexpr (WS) {
        wp   = (const short*)(ws + WS_W);
        epad = (const float*)(ws + WS_EPAD);
        xpad = (const float*)(ws + WS_XPAD);
    }

    int iw[3], jw[3], iru[3], jru[3];
    float tr_[3];
    #pragma unroll
    for (int r = 0; r < 3; ++r) {
        iw[r]  = i0 + 16 * r + l15;
        jw[r]  = j0 + 16 * r + l15;
        iru[r] = (iw[r] < NN) ? iw[r] : NN - 1;
        jru[r] = (jw[r] < NN) ? jw[r] : NN - 1;
        tr_[r] = fmaxf(dtime[iru[r]], 1e-8f);
    }

    // ---- batch-invariant: W fragments (held in regs for ALL iterations) + bias ----
    bf16x8 wfx[3][3], wfd[3][3];
    #pragma unroll
    for (int ks = 0; ks < 3; ++ks)
        #pragma unroll
        for (int wr = 0; wr < 3; ++wr) {
            wfx[ks][wr] = wload<WS>(wp, gW, 0, jw[wr], jru[wr], ks * 32 + lk * 8, ks == 2);
            wfd[ks][wr] = wload<WS>(wp, gW, 1, jw[wr], jru[wr], ks * 32 + lk * 8, ks == 2);
        }
    float bjv[3][4];
    #pragma unroll
    for (int wr = 0; wr < 3; ++wr) {
        const int jb = j0 + 16 * wr + lk * 4;
        if (jb + 3 < NN) {
            f32x4u t = *(const f32x4u*)(bias + jb);
            bjv[wr][0] = t.x; bjv[wr][1] = t.y; bjv[wr][2] = t.z; bjv[wr][3] = t.w;
        } else {
            #pragma unroll
            for (int q = 0; q < 4; ++q) bjv[wr][q] = (jb + q < NN) ? bias[jb + q] : 0.f;
        }
    }

    // zero tails once
    if (tid < 8) { sE[0][NN * EPW + tid] = 0.f; sE[1][NN * EPW + tid] = 0.f; }
    if (tid < 4) sD[NN * EPW + tid] = 0;

    // ---- prologue: stage batch b0 into buffer 0 ----
    const int b0 = (int)blockIdx.x;
    {
        const float* Eb = gevecs + (size_t)b0 * NN2;
        if (WS && b0 == B - 1) Eb = epad;
        stageE<WS>(Eb, sE[0], tid, wave, lane);
        if (tid < 96) sLam[0][tid] = (tid < NN) ? gevals[(size_t)b0 * NN + tid] : 3e38f;
    }
    __syncthreads();   // E(b0) + sLam[0] ready

    // ---- persistent loop ----
    for (int it = 0, b = b0; b < B; ++it, b += gridB) {
        const int  p  = it & 1;
        const int  bn = b + gridB;
        const bool hn = bn < B;

        // ===== TOP: prefetch next E (into the buffer last read a full iteration ago) =====
        if (hn) {
            const float* Ebn = gevecs + (size_t)bn * NN2;
            if (WS && bn == B - 1) Ebn = epad;
            stageE<WS>(Ebn, sE[1 - p], tid, wave, lane);
        }
        float lamn = 3e38f;
        if (hn && tid < NN) lamn = gevals[(size_t)bn * NN + tid];

        // ===== GEMM1: D = (E .* exp(-t_i lam_k)) @ E^T  (reads sE[p]) =====
        f32x4 acc1[3][3];
        #pragma unroll
        for (int c = 0; c < 3; ++c)
            #pragma unroll
            for (int r = 0; r < 3; ++r) acc1[c][r] = (f32x4){0.f, 0.f, 0.f, 0.f};

        const float* sEp = sE[p];
        #pragma unroll
        for (int ks = 0; ks < 3; ++ks) {
            const int k0 = ks * 32 + lk * 8;
            f32x4 la  = *(const f32x4*)&sLam[p][k0];
            f32x4 lb4 = *(const f32x4*)&sLam[p][k0 + 4];
            float l8_[8] = {la.x, la.y, la.z, la.w, lb4.x, lb4.y, lb4.z, lb4.w};

            bf16x8 ef[3], af[3];
            #pragma unroll
            for (int c = 0; c < 3; ++c) {
                f32x4 lo = *(const f32x4*)&sEp[jru[c] * EPW + k0];
                f32x4 hi = *(const f32x4*)&sEp[jru[c] * EPW + k0 + 4];
                #pragma unroll
                for (int q = 0; q < 4; ++q) { ef[c][q] = f2bf(lo[q]); ef[c][q + 4] = f2bf(hi[q]); }
            }
            #pragma unroll
            for (int r = 0; r < 3; ++r) {
                f32x4 lo = *(const f32x4*)&sEp[iru[r] * EPW + k0];
                f32x4 hi = *(const f32x4*)&sEp[iru[r] * EPW + k0 + 4];
                #pragma unroll
                for (int q = 0; q < 4; ++q) {
                    af[r][q]     = f2bf(lo[q] * __expf(-tr_[r] * l8_[q]));
                    af[r][q + 4] = f2bf(hi[q] * __expf(-tr_[r] * l8_[q + 4]));
                }
            }
            #pragma unroll
            for (int c = 0; c < 3; ++c)
                #pragma unroll
                for (int r = 0; r < 3; ++r)
                    acc1[c][r] = __builtin_amdgcn_mfma_f32_16x16x32_bf16(ef[c], af[r], acc1[c][r], 0, 0, 0);
        }

        // ===== x fragments for CURRENT batch (issued now; consumed after B3) =====
        const float* xbb = gx + (size_t)b * NN2;
        bool xvec = true;
        if (b == B - 1) { if (WS) xbb = xpad; else xvec = false; }
        float xr[3][3][8];
        #pragma unroll
        for (int xc = 0; xc < 3; ++xc)
            #pragma unroll
            for (int ks = 0; ks < 3; ++ks) {
                const int off = iru[xc] * NN + ks * 32 + lk * 8;
                if (xvec) {
                    f32x4u a  = *(const f32x4u*)(xbb + off);
                    f32x4u b4 = *(const f32x4u*)(xbb + off + 4);
                    xr[xc][ks][0] = a.x;  xr[xc][ks][1] = a.y;
                    xr[xc][ks][2] = a.z;  xr[xc][ks][3] = a.w;
                    xr[xc][ks][4] = b4.x; xr[xc][ks][5] = b4.y;
                    xr[xc][ks][6] = b4.z; xr[xc][ks][7] = b4.w;
                } else {
                    #pragma unroll
                    for (int q = 0; q < 8; ++q) {
                        int o = off + q;
                        xr[xc][ks][q] = xbb[(o < NN2) ? o : (NN2 - 1)];
                    }
                }
            }

        // ===== D -> sD (acc1 dies here) =====
        #pragma unroll
        for (int c = 0; c < 3; ++c) {
            const int jb = j0 + 16 * c + lk * 4;
            if (jb < EPW) {
                #pragma unroll
                for (int r = 0; r < 3; ++r) {
                    if (iw[r] < NN) {
                        bf16x4 v = {f2bf(acc1[c][r][0]), f2bf(acc1[c][r][1]),
                                    f2bf(acc1[c][r][2]), f2bf(acc1[c][r][3])};
                        *(bf16x4*)&sD[iw[r] * EPW + jb] = v;
                    }
                }
            }
        }
        // sLam for next batch (disjoint buffer; read only after next __syncthreads)
        if (hn && tid < 96) sLam[1 - p][tid] = (tid < NN) ? lamn : 3e38f;

        // ===== B3 (raw: lgkm drain only — DMA + x loads stay in flight) =====
        asm volatile("s_waitcnt lgkmcnt(0)" ::: "memory");
        __builtin_amdgcn_s_barrier();
        __builtin_amdgcn_sched_barrier(0);

        // ===== GEMM2: out = x@W1^T + D@W2^T (W from regs; bias pre-folded) =====
        f32x4 acc2[3][3];
        #pragma unroll
        for (int wr = 0; wr < 3; ++wr)
            #pragma unroll
            for (int xc = 0; xc < 3; ++xc) {
                acc2[wr][xc][0] = bjv[wr][0]; acc2[wr][xc][1] = bjv[wr][1];
                acc2[wr][xc][2] = bjv[wr][2]; acc2[wr][xc][3] = bjv[wr][3];
            }

        #pragma unroll
        for (int ks = 0; ks < 3; ++ks) {
            bf16x8 xf[3];
            #pragma unroll
            for (int xc = 0; xc < 3; ++xc)
                #pragma unroll
                for (int q = 0; q < 8; ++q) xf[xc][q] = f2bf(xr[xc][ks][q]);
            #pragma unroll
            for (int wr = 0; wr < 3; ++wr)
                #pragma unroll
                for (int xc = 0; xc < 3; ++xc)
                    acc2[wr][xc] = __builtin_amdgcn_mfma_f32_16x16x32_bf16(
                        wfx[ks][wr], xf[xc], acc2[wr][xc], 0, 0, 0);
        }
        #pragma unroll
        for (int ks = 0; ks < 3; ++ks) {
            const int k0 = ks * 32 + lk * 8;
            bf16x8 df[3];
            #pragma unroll
            for (int xc = 0; xc < 3; ++xc) {
                bf16x4 lo = *(const bf16x4*)&sD[iru[xc] * EPW + k0];
                bf16x4 hi = *(const bf16x4*)&sD[iru[xc] * EPW + k0 + 4];
                #pragma unroll
                for (int q = 0; q < 4; ++q) { df[xc][q] = lo[q]; df[xc][q + 4] = hi[q]; }
            }
            #pragma unroll
            for (int wr = 0; wr < 3; ++wr)
                #pragma unroll
                for (int xc = 0; xc < 3; ++xc)
                    acc2[wr][xc] = __builtin_amdgcn_mfma_f32_16x16x32_bf16(
                        wfd[ks][wr], df[xc], acc2[wr][xc], 0, 0, 0);
        }

        // ===== direct vectorized stores =====
        {
            float* __restrict__ gb = out + (size_t)b * NN2;
            #pragma unroll
            for (int wr = 0; wr < 3; ++wr) {
                const int jb = j0 + 16 * wr + lk * 4;
                #pragma unroll
                for (int xc = 0; xc < 3; ++xc) {
                    const int i = iw[xc];
                    if (i < NN) {
                        if (jb + 3 < NN) {
                            f32x4u v;
                            v.x = acc2[wr][xc][0]; v.y = acc2[wr][xc][1];
                            v.z = acc2[wr][xc][2]; v.w = acc2[wr][xc][3];
                            *(f32x4u*)&gb[i * NN + jb] = v;
                        } else {
                            #pragma unroll
                            for (int q = 0; q < 4; ++q)
                                if (jb + q < NN) gb[i * NN + jb + q] = acc2[wr][xc][q];
                        }
                    }
                }
            }
        }

        // B1(next): vmcnt(0)+lgkmcnt(0)+barrier -> E(bn) + sLam ready (DMA had ~full iter slack)
        if (hn) __syncthreads();
    }
}

extern "C" void kernel_launch(void* const* d_in, const int* in_sizes, int n_in,
                              void* d_out, int out_size, void* d_ws, size_t ws_size,
                              hipStream_t stream)
{
    const float* x     = (const float*)d_in[0];
    const float* evals = (const float*)d_in[1];
    const float* evecs = (const float*)d_in[2];
    const float* dtime = (const float*)d_in[3];
    const float* W     = (const float*)d_in[4];
    const float* bias  = (const float*)d_in[5];
    float* out = (float*)d_out;

    const int B = in_sizes[1] / NN;   // evals is (B, 87)
    const int gridB = (B < GRIDB) ? B : GRIDB;

    if (ws_size >= (size_t)WS_NEED) {
        const int prep_elems = 2 * WPANEL + 2 * PAD_N;
        prep<<<(prep_elems + NT - 1) / NT, NT, 0, stream>>>(W, evecs, x, B, (char*)d_ws);
        fused<true><<<dim3(gridB), dim3(NT), 0, stream>>>(x, evals, evecs, dtime, W, bias,
                                                          (const char*)d_ws, B, gridB, out);
    } else {
        fused<false><<<dim3(gridB), dim3(NT), 0, stream>>>(x, evals, evecs, dtime, W, bias,
                                                           nullptr, B, gridB, out);
    }
}

// Round 22
// 86.892 us; speedup vs baseline: 1.0231x; 1.0223x over previous
//
#include <hip/hip_runtime.h>
#include <hip/hip_bf16.h>
#include <math.h>

#define NN    87
#define NN2   (NN * NN)          // 7569
#define EPW   92                 // panel width
#define EF1   (NN * EPW + 8)     // 8012 floats per E buffer (incl zero tail)
#define SDN   (NN * EPW + 4)     // 8008 shorts: sD + zero tail
#define WPH   104                // ws W-panel row stride (shorts)
#define WPANEL (96 * WPH)        // 9984 shorts
#define NT    256                // prep block size
#define FT    768                // fused block size: 12 waves = 3/SIMD
#define GRIDB 256                // 1 block/CU, 16 batches per block

// ws layout (bytes)
#define PAD_N    8360
#define WS_W     0               // 2 bf16 W panels: 39936 B
#define WS_EPAD  (2 * WPANEL * 2)
#define WS_XPAD  (WS_EPAD + PAD_N * 4)
#define WS_NEED  (WS_XPAD + PAD_N * 4)

typedef __attribute__((ext_vector_type(8))) short bf16x8;
typedef __attribute__((ext_vector_type(4))) short bf16x4;
typedef __attribute__((ext_vector_type(4))) float f32x4;
typedef float f32x4u __attribute__((ext_vector_type(4), aligned(4)));

__device__ __forceinline__ short f2bf(float f) {
    __hip_bfloat16 h = __float2bfloat16(f);
    return *(short*)&h;
}

__device__ __forceinline__ void gl16(const float* g, float* l) {
    __builtin_amdgcn_global_load_lds(
        (const __attribute__((address_space(1))) void*)g,
        (__attribute__((address_space(3))) void*)l, 16, 0, 0);
}

// W panels + padded copies of LAST batch's E and x
__global__ void prep(const float* __restrict__ W, const float* __restrict__ evecs,
                     const float* __restrict__ x, int B, char* __restrict__ ws)
{
    int idx = (int)blockIdx.x * NT + (int)threadIdx.x;
    short* wpp = (short*)(ws + WS_W);
    float* ep  = (float*)(ws + WS_EPAD);
    float* xp  = (float*)(ws + WS_XPAD);
    if (idx < 2 * WPANEL) {
        int p = idx / WPANEL, rem = idx - p * WPANEL;
        int r = rem / WPH, c = rem - r * WPH;
        short v = 0;
        if (r < NN && c < NN) v = f2bf(W[r * (2 * NN) + p * NN + c]);
        wpp[idx] = v;
    }
    int i2 = idx - 2 * WPANEL;
    if (i2 >= 0 && i2 < PAD_N) ep[i2] = (i2 < NN2) ? evecs[(size_t)(B - 1) * NN2 + i2] : 0.f;
    int i3 = i2 - PAD_N;
    if (i3 >= 0 && i3 < PAD_N) xp[i3] = (i3 < NN2) ? x[(size_t)(B - 1) * NN2 + i3] : 0.f;
}

template <bool WS>
__device__ __forceinline__ bf16x8 wload(const short* __restrict__ wp,
                                        const float* __restrict__ gW,
                                        int panel, int jrow, int jcl, int k0, bool tailKs)
{
    if constexpr (WS) {
        return *(const bf16x8*)&wp[panel * WPANEL + jrow * WPH + k0];
    } else {
        float v[8];
        if (!tailKs) {
            f32x4u a  = *(const f32x4u*)(gW + jcl * (2 * NN) + panel * NN + k0);
            f32x4u b4 = *(const f32x4u*)(gW + jcl * (2 * NN) + panel * NN + k0 + 4);
            v[0] = a.x; v[1] = a.y; v[2] = a.z; v[3] = a.w;
            v[4] = b4.x; v[5] = b4.y; v[6] = b4.z; v[7] = b4.w;
        } else {
            #pragma unroll
            for (int q = 0; q < 8; ++q) {
                int k = k0 + q;
                v[q] = (k < NN) ? gW[jcl * (2 * NN) + panel * NN + k] : 0.f;
            }
        }
        bf16x8 o;
        #pragma unroll
        for (int q = 0; q < 8; ++q) o[q] = f2bf(v[q]);
        return o;
    }
}

// Stage one batch's E into a given sE buffer (12-wave version)
template <bool WS>
__device__ __forceinline__ void stageE(const float* __restrict__ Eb, float* __restrict__ sEb,
                                       int tid, int wave, int lane)
{
    if constexpr (WS) {
        for (int vc = wave; vc < 32; vc += 12) {
            int p   = vc * 256 + lane * 4;
            int row = p / EPW;
            int col = p - row * EPW;
            const float* g = Eb + row * NN + col;   // col>=87 spills to next row: finite, masked
            if (vc < 31) gl16(g, &sEb[vc * 256]);
            else if (lane < 17) gl16(g, &sEb[vc * 256]);
        }
    } else {
        for (int u = tid; u < NN * 22; u += FT) {
            int r = u / 22, sg = u - r * 22, c = sg * 4;
            const float* pE = Eb + r * NN + c;
            if (sg < 21) *(f32x4*)&sEb[r * EPW + c] = *(const f32x4u*)pE;
            else { f32x4 t; t.x = pE[0]; t.y = pE[1]; t.z = pE[2]; t.w = 0.f;
                   *(f32x4*)&sEb[r * EPW + c] = t; }
        }
        for (int u = tid; u < NN * 4; u += FT) {
            int r = u >> 2, c = 88 + (u & 3);
            sEb[r * EPW + c] = 0.f;
        }
    }
}

template <bool WS>
__global__ __launch_bounds__(FT, 1)
void fused(const float* __restrict__ gx, const float* __restrict__ gevals,
           const float* __restrict__ gevecs, const float* __restrict__ dtime,
           const float* __restrict__ gW, const float* __restrict__ bias,
           const char* __restrict__ ws, int B, int gridB, float* __restrict__ out)
{
    __shared__ __align__(16) float sE[2][EF1];   // 64096 B (double-buffered E)
    __shared__ __align__(16) short sD[SDN];      // 16016 B
    __shared__ float sLam[2][96];                // 768 B
    // total 80880 B -> 1 block of 12 waves per CU (3 waves/SIMD)

    const int tid  = (int)threadIdx.x;
    const int lane = tid & 63;
    const int wave = tid >> 6;                   // 0..11
    const int l15  = lane & 15;
    const int lk   = lane >> 4;
    const int i0   = (wave >> 1) * 16;           // 6 i-frags of 16 rows
    const int j0   = (wave & 1) * 48;            // 2 j-halves of 48 cols

    const short* wp   = nullptr;
    const float* epad = nullptr;
    const float* xpad = nullptr;
    if constexpr (WS) {
        wp   = (const short*)(ws + WS_W);
        epad = (const float*)(ws + WS_EPAD);
        xpad = (const float*)(ws + WS_XPAD);
    }

    // single i-frag per wave; 3 j-frags
    const int iw  = i0 + l15;                    // write row (may be >= 87)
    const int iru = (iw < NN) ? iw : NN - 1;     // clamped read row
    const float tr_ = fmaxf(dtime[iru], 1e-8f);
    int jw[3], jru[3];
    #pragma unroll
    for (int c = 0; c < 3; ++c) {
        jw[c]  = j0 + 16 * c + l15;
        jru[c] = (jw[c] < NN) ? jw[c] : NN - 1;
    }

    // ---- batch-invariant: W fragments (held in regs for ALL iterations) + bias ----
    bf16x8 wfx[3][3], wfd[3][3];
    #pragma unroll
    for (int ks = 0; ks < 3; ++ks)
        #pragma unroll
        for (int wr = 0; wr < 3; ++wr) {
            wfx[ks][wr] = wload<WS>(wp, gW, 0, jw[wr], jru[wr], ks * 32 + lk * 8, ks == 2);
            wfd[ks][wr] = wload<WS>(wp, gW, 1, jw[wr], jru[wr], ks * 32 + lk * 8, ks == 2);
        }
    float bjv[3][4];
    #pragma unroll
    for (int wr = 0; wr < 3; ++wr) {
        const int jb = j0 + 16 * wr + lk * 4;
        if (jb + 3 < NN) {
            f32x4u t = *(const f32x4u*)(bias + jb);
            bjv[wr][0] = t.x; bjv[wr][1] = t.y; bjv[wr][2] = t.z; bjv[wr][3] = t.w;
        } else {
            #pragma unroll
            for (int q = 0; q < 4; ++q) bjv[wr][q] = (jb + q < NN) ? bias[jb + q] : 0.f;
        }
    }

    // zero tails once
    if (tid < 8) { sE[0][NN * EPW + tid] = 0.f; sE[1][NN * EPW + tid] = 0.f; }
    if (tid < 4) sD[NN * EPW + tid] = 0;

    // ---- prologue: stage batch b0 into buffer 0 ----
    const int b0 = (int)blockIdx.x;
    {
        const float* Eb = gevecs + (size_t)b0 * NN2;
        if (WS && b0 == B - 1) Eb = epad;
        stageE<WS>(Eb, sE[0], tid, wave, lane);
        if (tid < 96) sLam[0][tid] = (tid < NN) ? gevals[(size_t)b0 * NN + tid] : 3e38f;
    }
    __syncthreads();   // E(b0) + sLam[0] ready

    // ---- persistent loop ----
    for (int it = 0, b = b0; b < B; ++it, b += gridB) {
        const int  p  = it & 1;
        const int  bn = b + gridB;
        const bool hn = bn < B;

        // ===== TOP: prefetch next E (into the buffer last read a full iteration ago) =====
        if (hn) {
            const float* Ebn = gevecs + (size_t)bn * NN2;
            if (WS && bn == B - 1) Ebn = epad;
            stageE<WS>(Ebn, sE[1 - p], tid, wave, lane);
        }
        float lamn = 3e38f;
        if (hn && tid < NN) lamn = gevals[(size_t)bn * NN + tid];

        // ===== GEMM1: D = (E .* exp(-t_i lam_k)) @ E^T  (reads sE[p]) =====
        f32x4 acc1[3];
        #pragma unroll
        for (int c = 0; c < 3; ++c) acc1[c] = (f32x4){0.f, 0.f, 0.f, 0.f};

        const float* sEp = sE[p];
        #pragma unroll
        for (int ks = 0; ks < 3; ++ks) {
            const int k0 = ks * 32 + lk * 8;
            f32x4 la  = *(const f32x4*)&sLam[p][k0];
            f32x4 lb4 = *(const f32x4*)&sLam[p][k0 + 4];
            float l8_[8] = {la.x, la.y, la.z, la.w, lb4.x, lb4.y, lb4.z, lb4.w};

            bf16x8 ef[3], af;
            #pragma unroll
            for (int c = 0; c < 3; ++c) {
                f32x4 lo = *(const f32x4*)&sEp[jru[c] * EPW + k0];
                f32x4 hi = *(const f32x4*)&sEp[jru[c] * EPW + k0 + 4];
                #pragma unroll
                for (int q = 0; q < 4; ++q) { ef[c][q] = f2bf(lo[q]); ef[c][q + 4] = f2bf(hi[q]); }
            }
            {
                f32x4 lo = *(const f32x4*)&sEp[iru * EPW + k0];
                f32x4 hi = *(const f32x4*)&sEp[iru * EPW + k0 + 4];
                #pragma unroll
                for (int q = 0; q < 4; ++q) {
                    af[q]     = f2bf(lo[q] * __expf(-tr_ * l8_[q]));
                    af[q + 4] = f2bf(hi[q] * __expf(-tr_ * l8_[q + 4]));
                }
            }
            #pragma unroll
            for (int c = 0; c < 3; ++c)
                acc1[c] = __builtin_amdgcn_mfma_f32_16x16x32_bf16(ef[c], af, acc1[c], 0, 0, 0);
        }

        // ===== x fragments for CURRENT batch (issued now; consumed after B3) =====
        const float* xbb = gx + (size_t)b * NN2;
        bool xvec = true;
        if (b == B - 1) { if (WS) xbb = xpad; else xvec = false; }
        float xr[3][8];
        #pragma unroll
        for (int ks = 0; ks < 3; ++ks) {
            const int off = iru * NN + ks * 32 + lk * 8;
            if (xvec) {
                f32x4u a  = *(const f32x4u*)(xbb + off);
                f32x4u b4 = *(const f32x4u*)(xbb + off + 4);
                xr[ks][0] = a.x;  xr[ks][1] = a.y;  xr[ks][2] = a.z;  xr[ks][3] = a.w;
                xr[ks][4] = b4.x; xr[ks][5] = b4.y; xr[ks][6] = b4.z; xr[ks][7] = b4.w;
            } else {
                #pragma unroll
                for (int q = 0; q < 8; ++q) {
                    int o = off + q;
                    xr[ks][q] = xbb[(o < NN2) ? o : (NN2 - 1)];
                }
            }
        }

        // ===== D -> sD (acc1 dies here) =====
        #pragma unroll
        for (int c = 0; c < 3; ++c) {
            const int jb = j0 + 16 * c + lk * 4;
            if (jb < EPW && iw < NN) {
                bf16x4 v = {f2bf(acc1[c][0]), f2bf(acc1[c][1]),
                            f2bf(acc1[c][2]), f2bf(acc1[c][3])};
                *(bf16x4*)&sD[iw * EPW + jb] = v;
            }
        }
        // sLam for next batch (disjoint buffer; read only after next __syncthreads)
        if (hn && tid < 96) sLam[1 - p][tid] = (tid < NN) ? lamn : 3e38f;

        // ===== B3 (raw: lgkm drain only — DMA + x loads stay in flight) =====
        asm volatile("s_waitcnt lgkmcnt(0)" ::: "memory");
        __builtin_amdgcn_s_barrier();
        __builtin_amdgcn_sched_barrier(0);

        // ===== GEMM2: out = x@W1^T + D@W2^T (W from regs; bias pre-folded) =====
        f32x4 acc2[3];
        #pragma unroll
        for (int wr = 0; wr < 3; ++wr) {
            acc2[wr][0] = bjv[wr][0]; acc2[wr][1] = bjv[wr][1];
            acc2[wr][2] = bjv[wr][2]; acc2[wr][3] = bjv[wr][3];
        }

        #pragma unroll
        for (int ks = 0; ks < 3; ++ks) {
            bf16x8 xf;
            #pragma unroll
            for (int q = 0; q < 8; ++q) xf[q] = f2bf(xr[ks][q]);
            #pragma unroll
            for (int wr = 0; wr < 3; ++wr)
                acc2[wr] = __builtin_amdgcn_mfma_f32_16x16x32_bf16(
                    wfx[ks][wr], xf, acc2[wr], 0, 0, 0);
        }
        #pragma unroll
        for (int ks = 0; ks < 3; ++ks) {
            const int k0 = ks * 32 + lk * 8;
            bf16x8 df;
            {
                bf16x4 lo = *(const bf16x4*)&sD[iru * EPW + k0];
                bf16x4 hi = *(const bf16x4*)&sD[iru * EPW + k0 + 4];
                #pragma unroll
                for (int q = 0; q < 4; ++q) { df[q] = lo[q]; df[q + 4] = hi[q]; }
            }
            #pragma unroll
            for (int wr = 0; wr < 3; ++wr)
                acc2[wr] = __builtin_amdgcn_mfma_f32_16x16x32_bf16(
                    wfd[ks][wr], df, acc2[wr], 0, 0, 0);
        }

        // ===== direct vectorized stores =====
        if (iw < NN) {
            float* __restrict__ gb = out + (size_t)b * NN2;
            #pragma unroll
            for (int wr = 0; wr < 3; ++wr) {
                const int jb = j0 + 16 * wr + lk * 4;
                if (jb + 3 < NN) {
                    f32x4u v;
                    v.x = acc2[wr][0]; v.y = acc2[wr][1];
                    v.z = acc2[wr][2]; v.w = acc2[wr][3];
                    *(f32x4u*)&gb[iw * NN + jb] = v;
                } else {
                    #pragma unroll
                    for (int q = 0; q < 4; ++q)
                        if (jb + q < NN) gb[iw * NN + jb + q] = acc2[wr][q];
                }
            }
        }

        // B1(next): vmcnt(0)+lgkmcnt(0)+barrier -> E(bn) + sLam ready (DMA had ~full iter slack)
        if (hn) __syncthreads();
    }
}

extern "C" void kernel_launch(void* const* d_in, const int* in_sizes, int n_in,
                              void* d_out, int out_size, void* d_ws, size_t ws_size,
                              hipStream_t stream)
{
    const float* x     = (const float*)d_in[0];
    const float* evals = (const float*)d_in[1];
    const float* evecs = (const float*)d_in[2];
    const float* dtime = (const float*)d_in[3];
    const float* W     = (const float*)d_in[4];
    const float* bias  = (const float*)d_in[5];
    float* out = (float*)d_out;

    const int B = in_sizes[1] / NN;   // evals is (B, 87)
    const int gridB = (B < GRIDB) ? B : GRIDB;

    if (ws_size >= (size_t)WS_NEED) {
        const int prep_elems = 2 * WPANEL + 2 * PAD_N;
        prep<<<(prep_elems + NT - 1) / NT, NT, 0, stream>>>(W, evecs, x, B, (char*)d_ws);
        fused<true><<<dim3(gridB), dim3(FT), 0, stream>>>(x, evals, evecs, dtime, W, bias,
                                                          (const char*)d_ws, B, gridB, out);
    } else {
        fused<false><<<dim3(gridB), dim3(FT), 0, stream>>>(x, evals, evecs, dtime, W, bias,
                                                           nullptr, B, gridB, out);
    }
}